// Round 1
// baseline (4614.639 us; speedup 1.0000x reference)
//
#include <hip/hip_runtime.h>
#include <math.h>

#define NROWS 32768
#define DIM   512
#define KCODE 8192
#define DECAYF 0.99f
#define OMDF   0.01f
#define EPSF   1e-5f
#define COMMITF 0.25f

// ---------------- ws layout (float offsets) ----------------
// inv_in : [NROWS]        @ 0
// inv_emb: [KCODE]        @ 32768
// bestV  : [2*NROWS]      @ 40960
// bestI  : [2*NROWS](int) @ 106496
// idx    : [NROWS](int)   @ 172032
// dw     : [KCODE*DIM]    @ 204800      <- zero region start
// counts : [KCODE]        @ 4399104
// lossAcc: [1]            @ 4407296
// nsum   : [1]            @ 4407297     <- zero region end (4407298)
// pre    : [KCODE]        @ 4407298
// csfin  : [KCODE]        @ 4415490
// total  : 4423682 floats (~17.7 MB)

// ---------------- out layout (float offsets) ----------------
// qst  @ 0         (16777216)
// loss @ 16777216  (1)
// idxf @ 16777217  (32768)
// cs   @ 16809985  (8192)
// emaw @ 16818177  (4194304)
// emb  @ 21012481  (4194304)   total 25206785

__device__ __forceinline__ float block_sum_256(float v) {
    __shared__ float sm[4];
    int lane = threadIdx.x & 63, wave = threadIdx.x >> 6;
    #pragma unroll
    for (int off = 32; off; off >>= 1) v += __shfl_down(v, off);
    if (lane == 0) sm[wave] = v;
    __syncthreads();
    if (threadIdx.x == 0) v = sm[0] + sm[1] + sm[2] + sm[3];
    return v; // valid on thread 0 only
}

// 4 rows per block (one wave per row): inv[row] = 1/max(||x_row||, 1e-12)
__global__ void k_rownorm_inv(const float* __restrict__ x, float* __restrict__ inv) {
    int wave = threadIdx.x >> 6;
    int lane = threadIdx.x & 63;
    int row = blockIdx.x * 4 + wave;
    const float* p = x + (size_t)row * DIM;
    float4 f1 = *(const float4*)&p[lane * 4];
    float4 f2 = *(const float4*)&p[256 + lane * 4];
    float s = f1.x*f1.x + f1.y*f1.y + f1.z*f1.z + f1.w*f1.w
            + f2.x*f2.x + f2.y*f2.y + f2.z*f2.z + f2.w*f2.w;
    #pragma unroll
    for (int off = 32; off; off >>= 1) s += __shfl_down(s, off);
    if (lane == 0) inv[row] = 1.0f / fmaxf(sqrtf(s), 1e-12f);
}

// Tiled fp32 matmul + running argmax. BM=128 rows, BN=128 codes, BD=8.
// grid (NROWS/128, 2): blockIdx.y = K-split half.
__launch_bounds__(256, 2)
__global__ void k_argmax(const float* __restrict__ X, const float* __restrict__ E,
                         const float* __restrict__ invx, const float* __restrict__ inve,
                         float* __restrict__ bestV, int* __restrict__ bestI) {
    constexpr int BM = 128, BN = 128, BD = 8;
    constexpr int KRANGE = KCODE / 2;
    __shared__ float As[BD][BM + 4];
    __shared__ float Bs[BD][BN + 4];
    __shared__ float rv[BM][17];
    __shared__ int   ri[BM][17];

    int tid = threadIdx.x;
    int rowBase = blockIdx.x * BM;
    int split = blockIdx.y;
    int kBase = split * KRANGE;
    int lr = tid >> 1;            // 0..127
    int c4 = (tid & 1) * 4;       // 0 or 4
    int tx = tid & 15, ty = tid >> 4;

    const float* Arow = X + (size_t)(rowBase + lr) * DIM + c4;
    float ia = invx[rowBase + lr];

    float bv[8]; int bi[8];
    #pragma unroll
    for (int i = 0; i < 8; i++) { bv[i] = -1e30f; bi[i] = 0; }

    for (int kt = 0; kt < KRANGE; kt += BN) {
        const float* Brow = E + (size_t)(kBase + kt + lr) * DIM + c4;
        float ib = inve[kBase + kt + lr];
        float acc[8][8];
        #pragma unroll
        for (int i = 0; i < 8; i++)
            #pragma unroll
            for (int j = 0; j < 8; j++) acc[i][j] = 0.f;

        for (int dt = 0; dt < DIM; dt += BD) {
            float4 a = *(const float4*)(Arow + dt);
            float4 b = *(const float4*)(Brow + dt);
            As[c4+0][lr] = a.x * ia; As[c4+1][lr] = a.y * ia;
            As[c4+2][lr] = a.z * ia; As[c4+3][lr] = a.w * ia;
            Bs[c4+0][lr] = b.x * ib; Bs[c4+1][lr] = b.y * ib;
            Bs[c4+2][lr] = b.z * ib; Bs[c4+3][lr] = b.w * ib;
            __syncthreads();
            #pragma unroll
            for (int d = 0; d < BD; d++) {
                float av[8], bw[8];
                *(float4*)&av[0] = *(const float4*)&As[d][ty * 8];
                *(float4*)&av[4] = *(const float4*)&As[d][ty * 8 + 4];
                *(float4*)&bw[0] = *(const float4*)&Bs[d][tx * 8];
                *(float4*)&bw[4] = *(const float4*)&Bs[d][tx * 8 + 4];
                #pragma unroll
                for (int i = 0; i < 8; i++)
                    #pragma unroll
                    for (int j = 0; j < 8; j++)
                        acc[i][j] = fmaf(av[i], bw[j], acc[i][j]);
            }
            __syncthreads();
        }
        // running argmax; columns visited in strictly ascending index order per thread,
        // so strict > keeps the first (lowest-index) max — matches argmin tie-break.
        #pragma unroll
        for (int i = 0; i < 8; i++) {
            #pragma unroll
            for (int j = 0; j < 8; j++) {
                float v = acc[i][j];
                if (v > bv[i]) { bv[i] = v; bi[i] = kBase + kt + tx * 8 + j; }
            }
        }
    }

    #pragma unroll
    for (int i = 0; i < 8; i++) { rv[ty * 8 + i][tx] = bv[i]; ri[ty * 8 + i][tx] = bi[i]; }
    __syncthreads();
    if (tid < BM) {
        float v = rv[tid][0]; int b = ri[tid][0];
        #pragma unroll
        for (int t = 1; t < 16; t++) {
            float v2 = rv[tid][t]; int b2 = ri[tid][t];
            if (v2 > v || (v2 == v && b2 < b)) { v = v2; b = b2; }
        }
        int n = rowBase + tid;
        bestV[split * NROWS + n] = v;
        bestI[split * NROWS + n] = b;
    }
}

__global__ void k_merge(const float* __restrict__ bestV, const int* __restrict__ bestI,
                        int* __restrict__ idx, float* __restrict__ idxf,
                        float* __restrict__ counts) {
    int n = blockIdx.x * 256 + threadIdx.x;
    float v0 = bestV[n];          int i0 = bestI[n];
    float v1 = bestV[NROWS + n];  int i1 = bestI[NROWS + n];
    int b = (v1 > v0 || (v1 == v0 && i1 < i0)) ? i1 : i0;
    idx[n] = b;
    idxf[n] = (float)b;
    atomicAdd(&counts[b], 1.0f);
}

// one block per row: write quantized_st, accumulate loss
__global__ void k_gather_loss(const float* __restrict__ X, const float* __restrict__ E,
                              const float* __restrict__ inve, const int* __restrict__ idx,
                              float* __restrict__ qst, float* __restrict__ lossAcc) {
    int n = blockIdx.x;
    int t = threadIdx.x;
    int k = idx[n];
    float ie = inve[k];
    const float* xr = X + (size_t)n * DIM;
    const float* er = E + (size_t)k * DIM;
    float2 x2 = *(const float2*)&xr[t * 2];
    float2 e2 = *(const float2*)&er[t * 2];
    float qx = e2.x * ie, qy = e2.y * ie;
    float dx = qx - x2.x, dy = qy - x2.y;
    float2 o; o.x = x2.x + dx; o.y = x2.y + dy;   // inputs + (q - inputs), same rounding as ref
    *(float2*)&qst[(size_t)n * DIM + t * 2] = o;
    float ls = block_sum_256(dx * dx + dy * dy);
    if (t == 0) atomicAdd(lossAcc, ls);
}

// one block per row: dw[idx[n]] += flat[n]
__global__ void k_scatter(const float* __restrict__ X, const float* __restrict__ invx,
                          const int* __restrict__ idx, float* __restrict__ dw) {
    int n = blockIdx.x;
    int t = threadIdx.x;
    int k = idx[n];
    float ix = invx[n];
    const float* xr = X + (size_t)n * DIM;
    float* dr = dw + (size_t)k * DIM;
    atomicAdd(&dr[t],       xr[t]       * ix);
    atomicAdd(&dr[t + 256], xr[t + 256] * ix);
}

__global__ void k_cs_pre(const float* __restrict__ emacs, const float* __restrict__ counts,
                         float* __restrict__ pre, float* __restrict__ nsum) {
    int k = blockIdx.x * 256 + threadIdx.x;
    float p = emacs[k] * DECAYF + OMDF * counts[k];
    pre[k] = p;
    float s = block_sum_256(p);
    if (threadIdx.x == 0) atomicAdd(nsum, s);
}

__global__ void k_cs_final(const float* __restrict__ pre, const float* __restrict__ nsum,
                           float* __restrict__ outCS, float* __restrict__ csfin,
                           const float* __restrict__ lossAcc, float* __restrict__ outLoss) {
    int k = blockIdx.x * 256 + threadIdx.x;
    float n = *nsum;
    float c = (pre[k] + EPSF) / (n + (float)KCODE * EPSF) * n;
    outCS[k] = c;
    csfin[k] = c;
    if (k == 0) *outLoss = COMMITF * (*lossAcc) / (float)(NROWS * DIM);
}

__global__ void k_emaw_embed(const float* __restrict__ emaw, const float* __restrict__ dw,
                             const float* __restrict__ csfin, float* __restrict__ outW,
                             float* __restrict__ outE) {
    int i = blockIdx.x * 256 + threadIdx.x;   // 0 .. K*D-1
    float v = emaw[i] * DECAYF + OMDF * dw[i];
    outW[i] = v;
    int k = i >> 9;
    outE[i] = v / fmaxf(csfin[k], EPSF);
}

extern "C" void kernel_launch(void* const* d_in, const int* in_sizes, int n_in,
                              void* d_out, int out_size, void* d_ws, size_t ws_size,
                              hipStream_t stream) {
    const float* inputs    = (const float*)d_in[0];
    const float* embedding = (const float*)d_in[1];
    const float* emacs     = (const float*)d_in[2];
    const float* emaw      = (const float*)d_in[3];
    float* out = (float*)d_out;
    float* ws  = (float*)d_ws;

    float* inv_in  = ws;
    float* inv_emb = ws + 32768;
    float* bestV   = ws + 40960;
    int*   bestI   = (int*)(ws + 106496);
    int*   idx     = (int*)(ws + 172032);
    float* dw      = ws + 204800;
    float* counts  = ws + 4399104;
    float* lossAcc = ws + 4407296;
    float* nsum    = ws + 4407297;
    float* pre     = ws + 4407298;
    float* csfin   = ws + 4415490;

    float* outQst  = out;
    float* outLoss = out + 16777216;
    float* outIdx  = out + 16777217;
    float* outCS   = out + 16809985;
    float* outW    = out + 16818177;
    float* outE    = out + 21012481;

    // zero dw + counts + lossAcc + nsum in one shot
    hipMemsetAsync(dw, 0, (size_t)(4194304 + 8192 + 2) * sizeof(float), stream);

    k_rownorm_inv<<<NROWS / 4, 256, 0, stream>>>(inputs, inv_in);
    k_rownorm_inv<<<KCODE / 4, 256, 0, stream>>>(embedding, inv_emb);
    k_argmax<<<dim3(NROWS / 128, 2), 256, 0, stream>>>(inputs, embedding, inv_in, inv_emb,
                                                       bestV, bestI);
    k_merge<<<NROWS / 256, 256, 0, stream>>>(bestV, bestI, idx, outIdx, counts);
    k_gather_loss<<<NROWS, 256, 0, stream>>>(inputs, embedding, inv_emb, idx, outQst, lossAcc);
    k_scatter<<<NROWS, 256, 0, stream>>>(inputs, inv_in, idx, dw);
    k_cs_pre<<<KCODE / 256, 256, 0, stream>>>(emacs, counts, pre, nsum);
    k_cs_final<<<KCODE / 256, 256, 0, stream>>>(pre, nsum, outCS, csfin, lossAcc, outLoss);
    k_emaw_embed<<<KCODE * DIM / 256, 256, 0, stream>>>(emaw, dw, csfin, outW, outE);
}

// Round 2
// 1497.878 us; speedup vs baseline: 3.0808x; 3.0808x over previous
//
#include <hip/hip_runtime.h>
#include <math.h>

#define NROWS 32768
#define DIM   512
#define KCODE 8192
#define DECAYF 0.99f
#define OMDF   0.01f
#define EPSF   1e-5f
#define COMMITF 0.25f

typedef _Float16 half8 __attribute__((ext_vector_type(8)));
typedef _Float16 half4v __attribute__((ext_vector_type(4)));
typedef float floatx16 __attribute__((ext_vector_type(16)));

// ---------------- ws layout (float offsets) ----------------
// inv_in : [32768]       @ 0
// inv_emb: [8192]        @ 32768
// bestV  : [2*32768]     @ 40960
// bestI  : [2*32768] int @ 106496
// idx    : [32768] int   @ 172032
// counts : [8192]        @ 204800   <- zeroed with lossAcc+nsum (8194 floats)
// lossAcc: [1]           @ 212992
// nsum   : [1]           @ 212993
// pre    : [8192]        @ 212994
// csfin  : [8192]        @ 221186
// Xh(f16): 16.7M halves  @ 229632  (8388608 float-slots)
// Xl(f16):               @ 8618240
// Eh(f16): 4.2M halves   @ 17006848 (2097152 float-slots)
// El(f16):               @ 19104000
// dw     : [8192*512]    @ 17006848  -- OVERLAYS Eh/El, used only after argmax
// total 21201152 floats = 84.8 MB

__device__ __forceinline__ float block_sum_256(float v) {
    __shared__ float sm[4];
    int lane = threadIdx.x & 63, wave = threadIdx.x >> 6;
    #pragma unroll
    for (int off = 32; off; off >>= 1) v += __shfl_down(v, off);
    if (lane == 0) sm[wave] = v;
    __syncthreads();
    if (threadIdx.x == 0) v = sm[0] + sm[1] + sm[2] + sm[3];
    return v; // valid on thread 0 only
}

__global__ void k_rownorm_inv(const float* __restrict__ x, float* __restrict__ inv) {
    int wave = threadIdx.x >> 6;
    int lane = threadIdx.x & 63;
    int row = blockIdx.x * 4 + wave;
    const float* p = x + (size_t)row * DIM;
    float4 f1 = *(const float4*)&p[lane * 4];
    float4 f2 = *(const float4*)&p[256 + lane * 4];
    float s = f1.x*f1.x + f1.y*f1.y + f1.z*f1.z + f1.w*f1.w
            + f2.x*f2.x + f2.y*f2.y + f2.z*f2.z + f2.w*f2.w;
    #pragma unroll
    for (int off = 32; off; off >>= 1) s += __shfl_down(s, off);
    if (lane == 0) inv[row] = 1.0f / fmaxf(sqrtf(s), 1e-12f);
}

// split normalized value into fp16 hi + fp16 lo*2^12 (lo stays normal)
__global__ void k_split(const float* __restrict__ src, const float* __restrict__ inv,
                        _Float16* __restrict__ hi, _Float16* __restrict__ lo) {
    const int i4 = (blockIdx.x * 256 + threadIdx.x) * 4;
    const float iv = inv[i4 >> 9];
    const float4 v = *(const float4*)&src[i4];
    float n0 = v.x * iv, n1 = v.y * iv, n2 = v.z * iv, n3 = v.w * iv;
    _Float16 h0 = (_Float16)n0, h1 = (_Float16)n1, h2 = (_Float16)n2, h3 = (_Float16)n3;
    half4v hv = {h0, h1, h2, h3};
    *(half4v*)&hi[i4] = hv;
    half4v lv = {(_Float16)((n0 - (float)h0) * 4096.f),
                 (_Float16)((n1 - (float)h1) * 4096.f),
                 (_Float16)((n2 - (float)h2) * 4096.f),
                 (_Float16)((n3 - (float)h3) * 4096.f)};
    *(half4v*)&lo[i4] = lv;
}

__device__ __forceinline__ void gld16(const _Float16* g, _Float16* l) {
    __builtin_amdgcn_global_load_lds(
        (const __attribute__((address_space(1))) void*)g,
        (__attribute__((address_space(3))) void*)l, 16, 0, 0);
}

// MFMA distance argmax: A = codes (E), B = rows (X); C[code][row] so argmax over
// codes is per-lane (regs). Dual-precision: v = accH + accC * 2^-12.
// Block: 128 rows x 128-code tiles, loops 32 tiles over its 4096-code split.
// LDS: 4 arrays [128][64] f16, BK=64, XOR bank swizzle slot = kchunk ^ (row&7).
__launch_bounds__(256, 2)
__global__ void k_argmax_mfma(const _Float16* __restrict__ Xh, const _Float16* __restrict__ Xl,
                              const _Float16* __restrict__ Eh, const _Float16* __restrict__ El,
                              float* __restrict__ bestV, int* __restrict__ bestI) {
    __shared__ __align__(16) _Float16 lds[4 * 128 * 64];  // Eh | El | Xh | Xl (8192 halves each)
    __shared__ float mV[128][2];
    __shared__ int   mI[128][2];

    const int tid  = threadIdx.x;
    const int w    = tid >> 6;
    const int lane = tid & 63;
    const int wc = w & 1, wr = w >> 1;          // wave: code-half, row-half
    const int c = lane & 31, h = lane >> 5;
    const int rowBase = blockIdx.x * 128;
    const int split   = blockIdx.y;

    // staging constants: lane covers row (lane>>3) of an 8-row group, 16B slot (lane&7)
    const int sr = lane >> 3;
    const int sg = (lane & 7) ^ (sr & 7);       // swizzled global k-chunk (16B units)

    const int rowA = wc * 64 + c;               // E rows (codes) this lane reads
    const int rowB = wr * 64 + c;               // X rows this lane reads
    const int cx = c & 7;

    float best0 = -1e30f, best1 = -1e30f;
    int bi0 = 0, bi1 = 0;
    const float SC = 1.0f / 4096.0f;

    for (int nt = 0; nt < 32; ++nt) {
        const int ntBase = split * 4096 + nt * 128;

        floatx16 accH00, accH01, accH10, accH11, accC00, accC01, accC10, accC11;
        #pragma unroll
        for (int r = 0; r < 16; ++r) {
            accH00[r] = 0.f; accH01[r] = 0.f; accH10[r] = 0.f; accH11[r] = 0.f;
            accC00[r] = 0.f; accC01[r] = 0.f; accC10[r] = 0.f; accC11[r] = 0.f;
        }

        for (int chunk = 0; chunk < 8; ++chunk) {
            const int kt = chunk * 64;
            #pragma unroll
            for (int j = 0; j < 4; ++j) {
                const int rl = w * 32 + j * 8 + sr;                  // 0..127
                const size_t gE = (size_t)(ntBase + rl) * DIM + kt + sg * 8;
                const size_t gX = (size_t)(rowBase + rl) * DIM + kt + sg * 8;
                _Float16* dBase = &lds[(w * 32 + j * 8) * 64];       // wave-uniform
                gld16(Eh + gE, dBase);
                gld16(El + gE, dBase + 8192);
                gld16(Xh + gX, dBase + 16384);
                gld16(Xl + gX, dBase + 24576);
            }
            __syncthreads();   // drains vmcnt -> LDS ready
            #pragma unroll
            for (int ks = 0; ks < 4; ++ks) {
                const int so = ((ks * 2 + h) ^ cx) * 8;
                const half8 ah0 = *(const half8*)&lds[rowA * 64 + so];
                const half8 ah1 = *(const half8*)&lds[(rowA + 32) * 64 + so];
                const half8 al0 = *(const half8*)&lds[8192 + rowA * 64 + so];
                const half8 al1 = *(const half8*)&lds[8192 + (rowA + 32) * 64 + so];
                const half8 bh0 = *(const half8*)&lds[16384 + rowB * 64 + so];
                const half8 bh1 = *(const half8*)&lds[16384 + (rowB + 32) * 64 + so];
                const half8 bl0 = *(const half8*)&lds[24576 + rowB * 64 + so];
                const half8 bl1 = *(const half8*)&lds[24576 + (rowB + 32) * 64 + so];

                accH00 = __builtin_amdgcn_mfma_f32_32x32x16_f16(ah0, bh0, accH00, 0, 0, 0);
                accC00 = __builtin_amdgcn_mfma_f32_32x32x16_f16(ah0, bl0, accC00, 0, 0, 0);
                accC00 = __builtin_amdgcn_mfma_f32_32x32x16_f16(al0, bh0, accC00, 0, 0, 0);

                accH01 = __builtin_amdgcn_mfma_f32_32x32x16_f16(ah0, bh1, accH01, 0, 0, 0);
                accC01 = __builtin_amdgcn_mfma_f32_32x32x16_f16(ah0, bl1, accC01, 0, 0, 0);
                accC01 = __builtin_amdgcn_mfma_f32_32x32x16_f16(al0, bh1, accC01, 0, 0, 0);

                accH10 = __builtin_amdgcn_mfma_f32_32x32x16_f16(ah1, bh0, accH10, 0, 0, 0);
                accC10 = __builtin_amdgcn_mfma_f32_32x32x16_f16(ah1, bl0, accC10, 0, 0, 0);
                accC10 = __builtin_amdgcn_mfma_f32_32x32x16_f16(al1, bh0, accC10, 0, 0, 0);

                accH11 = __builtin_amdgcn_mfma_f32_32x32x16_f16(ah1, bh1, accH11, 0, 0, 0);
                accC11 = __builtin_amdgcn_mfma_f32_32x32x16_f16(ah1, bl1, accC11, 0, 0, 0);
                accC11 = __builtin_amdgcn_mfma_f32_32x32x16_f16(al1, bh1, accC11, 0, 0, 0);
            }
            __syncthreads();   // protect LDS before next chunk's staging
        }

        // running argmax; explicit idx tie-break = first-index-of-max semantics
        #pragma unroll
        for (int r = 0; r < 16; ++r) {
            const int codeSub = (r & 3) + ((r >> 2) << 3) + (h << 2);
            const int code0 = ntBase + wc * 64 + codeSub;
            const int code1 = code0 + 32;
            float v;
            v = fmaf(accC00[r], SC, accH00[r]);
            if (v > best0 || (v == best0 && code0 < bi0)) { best0 = v; bi0 = code0; }
            v = fmaf(accC10[r], SC, accH10[r]);
            if (v > best0 || (v == best0 && code1 < bi0)) { best0 = v; bi0 = code1; }
            v = fmaf(accC01[r], SC, accH01[r]);
            if (v > best1 || (v == best1 && code0 < bi1)) { best1 = v; bi1 = code0; }
            v = fmaf(accC11[r], SC, accH11[r]);
            if (v > best1 || (v == best1 && code1 < bi1)) { best1 = v; bi1 = code1; }
        }
    }

    // merge the two lane-halves (same row, disjoint code subsets)
    {
        float ov = __shfl_xor(best0, 32); int oi = __shfl_xor(bi0, 32);
        if (ov > best0 || (ov == best0 && oi < bi0)) { best0 = ov; bi0 = oi; }
        ov = __shfl_xor(best1, 32); oi = __shfl_xor(bi1, 32);
        if (ov > best1 || (ov == best1 && oi < bi1)) { best1 = ov; bi1 = oi; }
    }
    if (h == 0) {
        mV[wr * 64 + c][wc] = best0;      mI[wr * 64 + c][wc] = bi0;
        mV[wr * 64 + 32 + c][wc] = best1; mI[wr * 64 + 32 + c][wc] = bi1;
    }
    __syncthreads();
    if (tid < 128) {
        float v0 = mV[tid][0]; int i0 = mI[tid][0];
        float v1 = mV[tid][1]; int i1 = mI[tid][1];
        float bv; int bidx;
        if (v1 > v0 || (v1 == v0 && i1 < i0)) { bv = v1; bidx = i1; }
        else                                  { bv = v0; bidx = i0; }
        bestV[split * NROWS + rowBase + tid] = bv;
        bestI[split * NROWS + rowBase + tid] = bidx;
    }
}

__global__ void k_merge(const float* __restrict__ bestV, const int* __restrict__ bestI,
                        int* __restrict__ idx, float* __restrict__ idxf,
                        float* __restrict__ counts) {
    int n = blockIdx.x * 256 + threadIdx.x;
    float v0 = bestV[n];          int i0 = bestI[n];
    float v1 = bestV[NROWS + n];  int i1 = bestI[NROWS + n];
    int b = (v1 > v0 || (v1 == v0 && i1 < i0)) ? i1 : i0;
    idx[n] = b;
    idxf[n] = (float)b;
    atomicAdd(&counts[b], 1.0f);
}

__global__ void k_gather_loss(const float* __restrict__ X, const float* __restrict__ E,
                              const float* __restrict__ inve, const int* __restrict__ idx,
                              float* __restrict__ qst, float* __restrict__ lossAcc) {
    int n = blockIdx.x;
    int t = threadIdx.x;
    int k = idx[n];
    float ie = inve[k];
    const float* xr = X + (size_t)n * DIM;
    const float* er = E + (size_t)k * DIM;
    float2 x2 = *(const float2*)&xr[t * 2];
    float2 e2 = *(const float2*)&er[t * 2];
    float qx = e2.x * ie, qy = e2.y * ie;
    float dx = qx - x2.x, dy = qy - x2.y;
    float2 o; o.x = x2.x + dx; o.y = x2.y + dy;
    *(float2*)&qst[(size_t)n * DIM + t * 2] = o;
    float ls = block_sum_256(dx * dx + dy * dy);
    if (t == 0) atomicAdd(lossAcc, ls);
}

__global__ void k_scatter(const float* __restrict__ X, const float* __restrict__ invx,
                          const int* __restrict__ idx, float* __restrict__ dw) {
    int n = blockIdx.x;
    int t = threadIdx.x;
    int k = idx[n];
    float ix = invx[n];
    const float* xr = X + (size_t)n * DIM;
    float* dr = dw + (size_t)k * DIM;
    atomicAdd(&dr[t],       xr[t]       * ix);
    atomicAdd(&dr[t + 256], xr[t + 256] * ix);
}

__global__ void k_cs_pre(const float* __restrict__ emacs, const float* __restrict__ counts,
                         float* __restrict__ pre, float* __restrict__ nsum) {
    int k = blockIdx.x * 256 + threadIdx.x;
    float p = emacs[k] * DECAYF + OMDF * counts[k];
    pre[k] = p;
    float s = block_sum_256(p);
    if (threadIdx.x == 0) atomicAdd(nsum, s);
}

__global__ void k_cs_final(const float* __restrict__ pre, const float* __restrict__ nsum,
                           float* __restrict__ outCS, float* __restrict__ csfin,
                           const float* __restrict__ lossAcc, float* __restrict__ outLoss) {
    int k = blockIdx.x * 256 + threadIdx.x;
    float n = *nsum;
    float c = (pre[k] + EPSF) / (n + (float)KCODE * EPSF) * n;
    outCS[k] = c;
    csfin[k] = c;
    if (k == 0) *outLoss = COMMITF * (*lossAcc) / (float)(NROWS * DIM);
}

__global__ void k_emaw_embed(const float* __restrict__ emaw, const float* __restrict__ dw,
                             const float* __restrict__ csfin, float* __restrict__ outW,
                             float* __restrict__ outE) {
    int i = blockIdx.x * 256 + threadIdx.x;
    float v = emaw[i] * DECAYF + OMDF * dw[i];
    outW[i] = v;
    int k = i >> 9;
    outE[i] = v / fmaxf(csfin[k], EPSF);
}

extern "C" void kernel_launch(void* const* d_in, const int* in_sizes, int n_in,
                              void* d_out, int out_size, void* d_ws, size_t ws_size,
                              hipStream_t stream) {
    const float* inputs    = (const float*)d_in[0];
    const float* embedding = (const float*)d_in[1];
    const float* emacs     = (const float*)d_in[2];
    const float* emaw      = (const float*)d_in[3];
    float* out = (float*)d_out;
    float* ws  = (float*)d_ws;

    float* inv_in  = ws;
    float* inv_emb = ws + 32768;
    float* bestV   = ws + 40960;
    int*   bestI   = (int*)(ws + 106496);
    int*   idx     = (int*)(ws + 172032);
    float* counts  = ws + 204800;
    float* lossAcc = ws + 212992;
    float* nsum    = ws + 212993;
    float* pre     = ws + 212994;
    float* csfin   = ws + 221186;
    _Float16* Xh   = (_Float16*)(ws + 229632);
    _Float16* Xl   = (_Float16*)(ws + 8618240);
    _Float16* Eh   = (_Float16*)(ws + 17006848);
    _Float16* El   = (_Float16*)(ws + 19104000);
    float* dw      = ws + 17006848;   // overlays Eh/El, only live after argmax

    float* outQst  = out;
    float* outLoss = out + 16777216;
    float* outIdx  = out + 16777217;
    float* outCS   = out + 16809985;
    float* outW    = out + 16818177;
    float* outE    = out + 21012481;

    hipMemsetAsync(counts, 0, (size_t)(8192 + 2) * sizeof(float), stream);
    k_rownorm_inv<<<NROWS / 4, 256, 0, stream>>>(inputs, inv_in);
    k_rownorm_inv<<<KCODE / 4, 256, 0, stream>>>(embedding, inv_emb);
    k_split<<<NROWS * DIM / 1024, 256, 0, stream>>>(inputs, inv_in, Xh, Xl);
    k_split<<<KCODE * DIM / 1024, 256, 0, stream>>>(embedding, inv_emb, Eh, El);
    k_argmax_mfma<<<dim3(NROWS / 128, 2), 256, 0, stream>>>(Xh, Xl, Eh, El, bestV, bestI);
    hipMemsetAsync(dw, 0, (size_t)KCODE * DIM * sizeof(float), stream);  // after argmax: overlay safe
    k_merge<<<NROWS / 256, 256, 0, stream>>>(bestV, bestI, idx, outIdx, counts);
    k_gather_loss<<<NROWS, 256, 0, stream>>>(inputs, embedding, inv_emb, idx, outQst, lossAcc);
    k_scatter<<<NROWS, 256, 0, stream>>>(inputs, inv_in, idx, dw);
    k_cs_pre<<<KCODE / 256, 256, 0, stream>>>(emacs, counts, pre, nsum);
    k_cs_final<<<KCODE / 256, 256, 0, stream>>>(pre, nsum, outCS, csfin, lossAcc, outLoss);
    k_emaw_embed<<<KCODE * DIM / 256, 256, 0, stream>>>(emaw, dw, csfin, outW, outE);
}

// Round 3
// 1069.441 us; speedup vs baseline: 4.3150x; 1.4006x over previous
//
#include <hip/hip_runtime.h>
#include <math.h>

#define NROWS 32768
#define DIM   512
#define KCODE 8192
#define DECAYF 0.99f
#define OMDF   0.01f
#define EPSF   1e-5f
#define COMMITF 0.25f
#define MARGIN 8e-4f

typedef _Float16 half8 __attribute__((ext_vector_type(8)));
typedef _Float16 half4v __attribute__((ext_vector_type(4)));
typedef _Float16 half2v __attribute__((ext_vector_type(2)));
typedef float floatx16 __attribute__((ext_vector_type(16)));

// ---------------- ws layout (float offsets), total 21200960 (~84.8 MB) ----------
// inv_in   @0        [32768]
// sV1      @32768    [65536]   (2 splits x 32768)      } dead after top2_merge,
// sV2      @98304    [65536]                           } then overlaid by:
// sI1 u16  @163840   [65536 u16 = 32768 slots]         }   rkey u64 @32768 (65536 fl)
//                                                          cntI     @98304  [8192]
//                                                          cursor   @106496 [8192]
//                                                          lossAcc  @114688, nsum @114689
//                                                          pre      @114692 [8192]
//                                                          csfin    @122884 [8192]
//                                                          offs     @131076 [8192]
//                                                          perm     @139268 [32768]
// list int @196608   [32768]
// flagCnt  @229376   [1]
// Xh (f16) @229440   [8388608 fl]  (inv_emb overlays first 8192 fl, dead pre-split_X)
// Xl (f16) @8618048  [8388608 fl]
// Eh (f16) @17006656 [2097152 fl]
// El (f16) @19103808 [2097152 fl] -> end 21200960

__device__ __forceinline__ float block_sum_256(float v) {
    __shared__ float sm[4];
    int lane = threadIdx.x & 63, wave = threadIdx.x >> 6;
    #pragma unroll
    for (int off = 32; off; off >>= 1) v += __shfl_down(v, off);
    if (lane == 0) sm[wave] = v;
    __syncthreads();
    if (threadIdx.x == 0) v = sm[0] + sm[1] + sm[2] + sm[3];
    return v; // valid on thread 0 only
}

__global__ void k_rownorm_inv(const float* __restrict__ x, float* __restrict__ inv) {
    int wave = threadIdx.x >> 6;
    int lane = threadIdx.x & 63;
    int row = blockIdx.x * 4 + wave;
    const float* p = x + (size_t)row * DIM;
    float4 f1 = *(const float4*)&p[lane * 4];
    float4 f2 = *(const float4*)&p[256 + lane * 4];
    float s = f1.x*f1.x + f1.y*f1.y + f1.z*f1.z + f1.w*f1.w
            + f2.x*f2.x + f2.y*f2.y + f2.z*f2.z + f2.w*f2.w;
    #pragma unroll
    for (int off = 32; off; off >>= 1) s += __shfl_down(s, off);
    if (lane == 0) inv[row] = 1.0f / fmaxf(sqrtf(s), 1e-12f);
}

__global__ void k_split(const float* __restrict__ src, const float* __restrict__ inv,
                        _Float16* __restrict__ hi, _Float16* __restrict__ lo) {
    const int i4 = (blockIdx.x * 256 + threadIdx.x) * 4;
    const float iv = inv[i4 >> 9];
    const float4 v = *(const float4*)&src[i4];
    float n0 = v.x * iv, n1 = v.y * iv, n2 = v.z * iv, n3 = v.w * iv;
    _Float16 h0 = (_Float16)n0, h1 = (_Float16)n1, h2 = (_Float16)n2, h3 = (_Float16)n3;
    half4v hv = {h0, h1, h2, h3};
    *(half4v*)&hi[i4] = hv;
    half4v lv = {(_Float16)((n0 - (float)h0) * 4096.f),
                 (_Float16)((n1 - (float)h1) * 4096.f),
                 (_Float16)((n2 - (float)h2) * 4096.f),
                 (_Float16)((n3 - (float)h3) * 4096.f)};
    *(half4v*)&lo[i4] = lv;
}

__device__ __forceinline__ void gld16(const _Float16* g, _Float16* l) {
    __builtin_amdgcn_global_load_lds(
        (const __attribute__((address_space(1))) void*)g,
        (__attribute__((address_space(3))) void*)l, 16, 0, 0);
}

__device__ __forceinline__ void top2_upd(float v, int i, float& v1, int& i1, float& v2) {
    if (v > v1) { v2 = v1; v1 = v; i1 = i; }
    else        { v2 = fmaxf(v2, v); }
}

// hi-only f16 screening pass. Block: 256 codes x 128 rows, wave tile 128x64
// (m=4,n=2). grid (256 row-tiles, 2 code-splits). LDS ~49KB -> 2 blocks/CU.
__launch_bounds__(256, 2)
__global__ void k_hi(const _Float16* __restrict__ Xh, const _Float16* __restrict__ Eh,
                     float* __restrict__ sV1, float* __restrict__ sV2,
                     unsigned short* __restrict__ sI1) {
    __shared__ __align__(16) _Float16 lds[24576];   // E [256][64] @0, X [128][64] @16384
    __shared__ float mV[128][2], mV2[128][2];
    __shared__ int   mI[128][2];

    const int tid  = threadIdx.x;
    const int w    = tid >> 6;
    const int lane = tid & 63;
    const int wc = w & 1, wr = w >> 1;
    const int c = lane & 31, h = lane >> 5;
    const int rowBase = blockIdx.x * 128;
    const int split   = blockIdx.y;
    const int sr = lane >> 3;
    const int sg = (lane & 7) ^ (sr & 7);
    const int cx = c & 7;
    const int rowB = wr * 64 + c;

    float v1a = -1e30f, v2a = -1e30f, v1b = -1e30f, v2b = -1e30f;
    int i1a = 0, i1b = 0;

    for (int nt = 0; nt < 16; ++nt) {
        const int ntBase = split * 4096 + nt * 256;
        floatx16 acc[4][2];
        #pragma unroll
        for (int i = 0; i < 4; ++i)
            #pragma unroll
            for (int j = 0; j < 2; ++j)
                #pragma unroll
                for (int r = 0; r < 16; ++r) acc[i][j][r] = 0.f;

        for (int chunk = 0; chunk < 8; ++chunk) {
            const int kt = chunk * 64;
            #pragma unroll
            for (int j = 0; j < 12; ++j) {
                const int u0 = w * 96 + j * 8;          // wave-uniform group base
                const int u  = u0 + sr;
                if (u0 < 256) {   // E rows
                    gld16(Eh + (size_t)(ntBase + u) * DIM + kt + sg * 8, &lds[u0 * 64]);
                } else {          // X rows
                    gld16(Xh + (size_t)(rowBase + u - 256) * DIM + kt + sg * 8,
                          &lds[16384 + (u0 - 256) * 64]);
                }
            }
            __syncthreads();
            #pragma unroll
            for (int ks = 0; ks < 4; ++ks) {
                const int so = ((ks * 2 + h) ^ cx) * 8;
                half8 a0 = *(const half8*)&lds[(wc * 128 + 0  + c) * 64 + so];
                half8 a1 = *(const half8*)&lds[(wc * 128 + 32 + c) * 64 + so];
                half8 a2 = *(const half8*)&lds[(wc * 128 + 64 + c) * 64 + so];
                half8 a3 = *(const half8*)&lds[(wc * 128 + 96 + c) * 64 + so];
                half8 b0 = *(const half8*)&lds[16384 + (rowB) * 64 + so];
                half8 b1 = *(const half8*)&lds[16384 + (rowB + 32) * 64 + so];
                acc[0][0] = __builtin_amdgcn_mfma_f32_32x32x16_f16(a0, b0, acc[0][0], 0, 0, 0);
                acc[1][0] = __builtin_amdgcn_mfma_f32_32x32x16_f16(a1, b0, acc[1][0], 0, 0, 0);
                acc[2][0] = __builtin_amdgcn_mfma_f32_32x32x16_f16(a2, b0, acc[2][0], 0, 0, 0);
                acc[3][0] = __builtin_amdgcn_mfma_f32_32x32x16_f16(a3, b0, acc[3][0], 0, 0, 0);
                acc[0][1] = __builtin_amdgcn_mfma_f32_32x32x16_f16(a0, b1, acc[0][1], 0, 0, 0);
                acc[1][1] = __builtin_amdgcn_mfma_f32_32x32x16_f16(a1, b1, acc[1][1], 0, 0, 0);
                acc[2][1] = __builtin_amdgcn_mfma_f32_32x32x16_f16(a2, b1, acc[2][1], 0, 0, 0);
                acc[3][1] = __builtin_amdgcn_mfma_f32_32x32x16_f16(a3, b1, acc[3][1], 0, 0, 0);
            }
            __syncthreads();
        }
        #pragma unroll
        for (int r = 0; r < 16; ++r) {
            const int codeSub = (r & 3) + ((r >> 2) << 3) + (h << 2);
            #pragma unroll
            for (int i = 0; i < 4; ++i) {
                const int code = ntBase + wc * 128 + i * 32 + codeSub;
                top2_upd(acc[i][0][r], code, v1a, i1a, v2a);
                top2_upd(acc[i][1][r], code, v1b, i1b, v2b);
            }
        }
    }

    // merge h-halves (disjoint code sets, same row)
    {
        float ov1 = __shfl_xor(v1a, 32); int oi1 = __shfl_xor(i1a, 32); float ov2 = __shfl_xor(v2a, 32);
        if (ov1 > v1a) { v2a = fmaxf(v1a, ov2); v1a = ov1; i1a = oi1; }
        else if (ov1 == v1a) { v2a = v1a; if (oi1 < i1a) i1a = oi1; }
        else { v2a = fmaxf(v2a, ov1); }
        ov1 = __shfl_xor(v1b, 32); oi1 = __shfl_xor(i1b, 32); ov2 = __shfl_xor(v2b, 32);
        if (ov1 > v1b) { v2b = fmaxf(v1b, ov2); v1b = ov1; i1b = oi1; }
        else if (ov1 == v1b) { v2b = v1b; if (oi1 < i1b) i1b = oi1; }
        else { v2b = fmaxf(v2b, ov1); }
    }
    if (h == 0) {
        mV[rowB][wc] = v1a; mV2[rowB][wc] = v2a; mI[rowB][wc] = i1a;
        mV[rowB + 32][wc] = v1b; mV2[rowB + 32][wc] = v2b; mI[rowB + 32][wc] = i1b;
    }
    __syncthreads();
    if (tid < 128) {
        float v1 = mV[tid][0], v2 = mV2[tid][0]; int i1 = mI[tid][0];
        float ov1 = mV[tid][1], ov2 = mV2[tid][1]; int oi1 = mI[tid][1];
        if (ov1 > v1) { v2 = fmaxf(v1, ov2); v1 = ov1; i1 = oi1; }
        else if (ov1 == v1) { v2 = v1; if (oi1 < i1) i1 = oi1; }
        else { v2 = fmaxf(v2, ov1); }
        const int n = rowBase + tid;
        sV1[split * NROWS + n] = v1;
        sV2[split * NROWS + n] = v2;
        sI1[split * NROWS + n] = (unsigned short)i1;
    }
}

__global__ void k_top2_merge(const float* __restrict__ sV1, const float* __restrict__ sV2,
                             const unsigned short* __restrict__ sI1,
                             float* __restrict__ outIdx, int* __restrict__ list,
                             int* __restrict__ flagCnt) {
    const int n = blockIdx.x * 256 + threadIdx.x;
    float a1 = sV1[n], a2 = sV2[n]; int ai = sI1[n];
    float b1 = sV1[NROWS + n], b2 = sV2[NROWS + n]; int bi = sI1[NROWS + n];
    float best, run; int bidx;
    if (b1 > a1) { best = b1; bidx = bi; run = fmaxf(a1, b2); }
    else         { best = a1; bidx = ai; run = fmaxf(a2, b1); }
    outIdx[n] = (float)bidx;
    if (best - run < MARGIN) {
        int p = atomicAdd(flagCnt, 1);
        list[p] = n;
    }
}

__device__ __forceinline__ unsigned long long encodeKey(float v, int idx) {
    unsigned u = __float_as_uint(v);
    u = (u & 0x80000000u) ? ~u : (u | 0x80000000u);
    return ((unsigned long long)u << 32) | (unsigned)(0xFFFFFFFFu - (unsigned)idx);
}

// dual-precision rescore of flagged rows (r2-identical numerics).
// grid 4096: t = bx&255 row-tile, s = bx>>8 code-split (512 codes each).
__launch_bounds__(256, 2)
__global__ void k_rescore(const _Float16* __restrict__ Xh, const _Float16* __restrict__ Xl,
                          const _Float16* __restrict__ Eh, const _Float16* __restrict__ El,
                          const int* __restrict__ list, const int* __restrict__ flagCnt,
                          unsigned long long* __restrict__ rkey) {
    const int cnt = *flagCnt;
    const int t = blockIdx.x & 255;
    const int s = blockIdx.x >> 8;
    if (t * 128 >= cnt) return;

    __shared__ __align__(16) _Float16 lds[32768];  // Eh|El|Xh|Xl, 8192 halves each
    __shared__ float mV[128][2];
    __shared__ int   mI[128][2];

    const int tid  = threadIdx.x;
    const int w    = tid >> 6;
    const int lane = tid & 63;
    const int wc = w & 1, wr = w >> 1;
    const int c = lane & 31, h = lane >> 5;
    const int sr = lane >> 3;
    const int sg = (lane & 7) ^ (sr & 7);
    const int rowA = wc * 64 + c;
    const int rowB = wr * 64 + c;
    const int cx = c & 7;

    int rows_j[4];
    #pragma unroll
    for (int j = 0; j < 4; ++j) {
        const int slot = t * 128 + w * 32 + j * 8 + sr;
        rows_j[j] = (slot < cnt) ? list[slot] : 0;
    }

    float best0 = -1e30f, best1 = -1e30f;
    int bi0 = 0, bi1 = 0;
    const float SC = 1.0f / 4096.0f;

    for (int nt = 0; nt < 4; ++nt) {
        const int ntBase = s * 512 + nt * 128;

        floatx16 accH00, accH01, accH10, accH11, accC00, accC01, accC10, accC11;
        #pragma unroll
        for (int r = 0; r < 16; ++r) {
            accH00[r] = 0.f; accH01[r] = 0.f; accH10[r] = 0.f; accH11[r] = 0.f;
            accC00[r] = 0.f; accC01[r] = 0.f; accC10[r] = 0.f; accC11[r] = 0.f;
        }

        for (int chunk = 0; chunk < 8; ++chunk) {
            const int kt = chunk * 64;
            #pragma unroll
            for (int j = 0; j < 4; ++j) {
                const int rl = w * 32 + j * 8 + sr;
                const size_t gE = (size_t)(ntBase + rl) * DIM + kt + sg * 8;
                const size_t gX = (size_t)rows_j[j] * DIM + kt + sg * 8;
                _Float16* dBase = &lds[(w * 32 + j * 8) * 64];
                gld16(Eh + gE, dBase);
                gld16(El + gE, dBase + 8192);
                gld16(Xh + gX, dBase + 16384);
                gld16(Xl + gX, dBase + 24576);
            }
            __syncthreads();
            #pragma unroll
            for (int ks = 0; ks < 4; ++ks) {
                const int so = ((ks * 2 + h) ^ cx) * 8;
                const half8 ah0 = *(const half8*)&lds[rowA * 64 + so];
                const half8 ah1 = *(const half8*)&lds[(rowA + 32) * 64 + so];
                const half8 al0 = *(const half8*)&lds[8192 + rowA * 64 + so];
                const half8 al1 = *(const half8*)&lds[8192 + (rowA + 32) * 64 + so];
                const half8 bh0 = *(const half8*)&lds[16384 + rowB * 64 + so];
                const half8 bh1 = *(const half8*)&lds[16384 + (rowB + 32) * 64 + so];
                const half8 bl0 = *(const half8*)&lds[24576 + rowB * 64 + so];
                const half8 bl1 = *(const half8*)&lds[24576 + (rowB + 32) * 64 + so];

                accH00 = __builtin_amdgcn_mfma_f32_32x32x16_f16(ah0, bh0, accH00, 0, 0, 0);
                accC00 = __builtin_amdgcn_mfma_f32_32x32x16_f16(ah0, bl0, accC00, 0, 0, 0);
                accC00 = __builtin_amdgcn_mfma_f32_32x32x16_f16(al0, bh0, accC00, 0, 0, 0);

                accH01 = __builtin_amdgcn_mfma_f32_32x32x16_f16(ah0, bh1, accH01, 0, 0, 0);
                accC01 = __builtin_amdgcn_mfma_f32_32x32x16_f16(ah0, bl1, accC01, 0, 0, 0);
                accC01 = __builtin_amdgcn_mfma_f32_32x32x16_f16(al0, bh1, accC01, 0, 0, 0);

                accH10 = __builtin_amdgcn_mfma_f32_32x32x16_f16(ah1, bh0, accH10, 0, 0, 0);
                accC10 = __builtin_amdgcn_mfma_f32_32x32x16_f16(ah1, bl0, accC10, 0, 0, 0);
                accC10 = __builtin_amdgcn_mfma_f32_32x32x16_f16(al1, bh0, accC10, 0, 0, 0);

                accH11 = __builtin_amdgcn_mfma_f32_32x32x16_f16(ah1, bh1, accH11, 0, 0, 0);
                accC11 = __builtin_amdgcn_mfma_f32_32x32x16_f16(ah1, bl1, accC11, 0, 0, 0);
                accC11 = __builtin_amdgcn_mfma_f32_32x32x16_f16(al1, bh1, accC11, 0, 0, 0);
            }
            __syncthreads();
        }

        #pragma unroll
        for (int r = 0; r < 16; ++r) {
            const int codeSub = (r & 3) + ((r >> 2) << 3) + (h << 2);
            const int code0 = ntBase + wc * 64 + codeSub;
            const int code1 = code0 + 32;
            float v;
            v = fmaf(accC00[r], SC, accH00[r]);
            if (v > best0 || (v == best0 && code0 < bi0)) { best0 = v; bi0 = code0; }
            v = fmaf(accC10[r], SC, accH10[r]);
            if (v > best0 || (v == best0 && code1 < bi0)) { best0 = v; bi0 = code1; }
            v = fmaf(accC01[r], SC, accH01[r]);
            if (v > best1 || (v == best1 && code0 < bi1)) { best1 = v; bi1 = code0; }
            v = fmaf(accC11[r], SC, accH11[r]);
            if (v > best1 || (v == best1 && code1 < bi1)) { best1 = v; bi1 = code1; }
        }
    }

    {
        float ov = __shfl_xor(best0, 32); int oi = __shfl_xor(bi0, 32);
        if (ov > best0 || (ov == best0 && oi < bi0)) { best0 = ov; bi0 = oi; }
        ov = __shfl_xor(best1, 32); oi = __shfl_xor(bi1, 32);
        if (ov > best1 || (ov == best1 && oi < bi1)) { best1 = ov; bi1 = oi; }
    }
    if (h == 0) {
        mV[rowB][wc] = best0;      mI[rowB][wc] = bi0;
        mV[rowB + 32][wc] = best1; mI[rowB + 32][wc] = bi1;
    }
    __syncthreads();
    if (tid < 128) {
        const int slot = t * 128 + tid;
        if (slot < cnt) {
            float v0 = mV[tid][0]; int i0 = mI[tid][0];
            float v1 = mV[tid][1]; int i1 = mI[tid][1];
            float bv; int bidx;
            if (v1 > v0 || (v1 == v0 && i1 < i0)) { bv = v1; bidx = i1; }
            else                                  { bv = v0; bidx = i0; }
            atomicMax(&rkey[list[slot]], encodeKey(bv, bidx));
        }
    }
}

__global__ void k_rescore_merge(const unsigned long long* __restrict__ rkey,
                                const int* __restrict__ list, const int* __restrict__ flagCnt,
                                float* __restrict__ outIdx) {
    const int slot = blockIdx.x * 256 + threadIdx.x;
    if (slot < *flagCnt) {
        const int row = list[slot];
        const unsigned long long key = rkey[row];
        const int code = (int)(0xFFFFFFFFu - (unsigned)(key & 0xFFFFFFFFull));
        outIdx[row] = (float)code;
    }
}

__global__ void k_hist(const float* __restrict__ outIdx, int* __restrict__ cntI) {
    const int n = blockIdx.x * 256 + threadIdx.x;
    atomicAdd(&cntI[(int)outIdx[n]], 1);
}

__global__ void k_gather_loss(const float* __restrict__ X, const _Float16* __restrict__ Eh,
                              const _Float16* __restrict__ El, const float* __restrict__ outIdx,
                              float* __restrict__ qst, float* __restrict__ lossAcc) {
    const int n = blockIdx.x;
    const int t = threadIdx.x;
    const int k = (int)outIdx[n];
    const float SC = 1.0f / 4096.0f;
    const float* xr = X + (size_t)n * DIM;
    float2 x2 = *(const float2*)&xr[t * 2];
    half2v eh = *(const half2v*)&Eh[(size_t)k * DIM + t * 2];
    half2v el = *(const half2v*)&El[(size_t)k * DIM + t * 2];
    float qx = (float)eh.x + (float)el.x * SC;
    float qy = (float)eh.y + (float)el.y * SC;
    float dx = qx - x2.x, dy = qy - x2.y;
    float2 o; o.x = x2.x + dx; o.y = x2.y + dy;
    *(float2*)&qst[(size_t)n * DIM + t * 2] = o;
    float ls = block_sum_256(dx * dx + dy * dy);
    if (t == 0) atomicAdd(lossAcc, ls);
}

__global__ void k_cs_pre(const float* __restrict__ emacs, const int* __restrict__ cntI,
                         float* __restrict__ pre, float* __restrict__ nsum) {
    const int k = blockIdx.x * 256 + threadIdx.x;
    float p = emacs[k] * DECAYF + OMDF * (float)cntI[k];
    pre[k] = p;
    float s = block_sum_256(p);
    if (threadIdx.x == 0) atomicAdd(nsum, s);
}

__global__ void k_cs_final(const float* __restrict__ pre, const float* __restrict__ nsum,
                           float* __restrict__ outCS, float* __restrict__ csfin,
                           const float* __restrict__ lossAcc, float* __restrict__ outLoss) {
    const int k = blockIdx.x * 256 + threadIdx.x;
    float n = *nsum;
    float c = (pre[k] + EPSF) / (n + (float)KCODE * EPSF) * n;
    outCS[k] = c;
    csfin[k] = c;
    if (k == 0) *outLoss = COMMITF * (*lossAcc) / (float)(NROWS * DIM);
}

__global__ void k_scan(const int* __restrict__ cntI, int* __restrict__ offs) {
    __shared__ int ps[1024];
    const int t = threadIdx.x;
    int loc[8], pref[8], s = 0;
    #pragma unroll
    for (int j = 0; j < 8; ++j) { loc[j] = cntI[t * 8 + j]; pref[j] = s; s += loc[j]; }
    ps[t] = s;
    __syncthreads();
    for (int d = 1; d < 1024; d <<= 1) {
        int x = (t >= d) ? ps[t - d] : 0;
        __syncthreads();
        ps[t] += x;
        __syncthreads();
    }
    const int base = ps[t] - s;   // exclusive prefix of this thread's chunk
    #pragma unroll
    for (int j = 0; j < 8; ++j) offs[t * 8 + j] = base + pref[j];
}

__global__ void k_bin(const float* __restrict__ outIdx, const int* __restrict__ offs,
                      int* __restrict__ cursor, int* __restrict__ perm) {
    const int n = blockIdx.x * 256 + threadIdx.x;
    const int k = (int)outIdx[n];
    const int pos = offs[k] + atomicAdd(&cursor[k], 1);
    perm[pos] = n;
}

// one block per code: dw accumulation + EMA weight + embedding, fused.
__global__ void k_dw_fused(const float* __restrict__ X, const float* __restrict__ inv_in,
                           const int* __restrict__ perm, const int* __restrict__ offs,
                           const int* __restrict__ cntI, const float* __restrict__ emaw,
                           const float* __restrict__ csfin,
                           float* __restrict__ outW, float* __restrict__ outE) {
    const int k = blockIdx.x;
    const int t = threadIdx.x;
    const int c = cntI[k];
    const int base = offs[k];
    float a0 = 0.f, a1 = 0.f;
    for (int i = 0; i < c; ++i) {
        const int row = perm[base + i];
        const float iv = inv_in[row];
        const float2 x = *(const float2*)&X[(size_t)row * DIM + t * 2];
        a0 = fmaf(x.x, iv, a0);
        a1 = fmaf(x.y, iv, a1);
    }
    const float2 w2 = *(const float2*)&emaw[(size_t)k * DIM + t * 2];
    const float w0 = w2.x * DECAYF + OMDF * a0;
    const float w1 = w2.y * DECAYF + OMDF * a1;
    float2 ow; ow.x = w0; ow.y = w1;
    *(float2*)&outW[(size_t)k * DIM + t * 2] = ow;
    const float cs = fmaxf(csfin[k], EPSF);
    float2 oe; oe.x = w0 / cs; oe.y = w1 / cs;
    *(float2*)&outE[(size_t)k * DIM + t * 2] = oe;
}

extern "C" void kernel_launch(void* const* d_in, const int* in_sizes, int n_in,
                              void* d_out, int out_size, void* d_ws, size_t ws_size,
                              hipStream_t stream) {
    const float* inputs    = (const float*)d_in[0];
    const float* embedding = (const float*)d_in[1];
    const float* emacs     = (const float*)d_in[2];
    const float* emaw      = (const float*)d_in[3];
    float* out = (float*)d_out;
    float* ws  = (float*)d_ws;

    float* inv_in  = ws;
    float* sV1     = ws + 32768;
    float* sV2     = ws + 98304;
    unsigned short* sI1 = (unsigned short*)(ws + 163840);
    int*   list    = (int*)(ws + 196608);
    int*   flagCnt = (int*)(ws + 229376);
    float* inv_emb = ws + 229440;            // overlays Xh head, dead before split_X
    _Float16* Xh   = (_Float16*)(ws + 229440);
    _Float16* Xl   = (_Float16*)(ws + 8618048);
    _Float16* Eh   = (_Float16*)(ws + 17006656);
    _Float16* El   = (_Float16*)(ws + 19103808);
    // overlays valid after k_top2_merge:
    unsigned long long* rkey = (unsigned long long*)(ws + 32768);
    int*   cntI    = (int*)(ws + 98304);
    int*   cursor  = (int*)(ws + 106496);
    float* lossAcc = ws + 114688;
    float* nsum    = ws + 114689;
    float* pre     = ws + 114692;
    float* csfin   = ws + 122884;
    int*   offs    = (int*)(ws + 131076);
    int*   perm    = (int*)(ws + 139268);

    float* outQst  = out;
    float* outLoss = out + 16777216;
    float* outIdx  = out + 16777217;
    float* outCS   = out + 16809985;
    float* outW    = out + 16818177;
    float* outE    = out + 21012481;

    hipMemsetAsync(flagCnt, 0, sizeof(int), stream);
    k_rownorm_inv<<<NROWS / 4, 256, 0, stream>>>(inputs, inv_in);
    k_rownorm_inv<<<KCODE / 4, 256, 0, stream>>>(embedding, inv_emb);
    k_split<<<KCODE * DIM / 1024, 256, 0, stream>>>(embedding, inv_emb, Eh, El);
    k_split<<<NROWS * DIM / 1024, 256, 0, stream>>>(inputs, inv_in, Xh, Xl);
    k_hi<<<dim3(NROWS / 128, 2), 256, 0, stream>>>(Xh, Eh, sV1, sV2, sI1);
    k_top2_merge<<<NROWS / 256, 256, 0, stream>>>(sV1, sV2, sI1, outIdx, list, flagCnt);
    // zero overlays: rkey(65536) + cntI(8192) + cursor(8192) + lossAcc + nsum
    hipMemsetAsync(ws + 32768, 0, (size_t)81922 * sizeof(float), stream);
    k_rescore<<<4096, 256, 0, stream>>>(Xh, Xl, Eh, El, list, flagCnt, rkey);
    k_rescore_merge<<<NROWS / 256, 256, 0, stream>>>(rkey, list, flagCnt, outIdx);
    k_hist<<<NROWS / 256, 256, 0, stream>>>(outIdx, cntI);
    k_gather_loss<<<NROWS, 256, 0, stream>>>(inputs, Eh, El, outIdx, outQst, lossAcc);
    k_cs_pre<<<KCODE / 256, 256, 0, stream>>>(emacs, cntI, pre, nsum);
    k_cs_final<<<KCODE / 256, 256, 0, stream>>>(pre, nsum, outCS, csfin, lossAcc, outLoss);
    k_scan<<<1, 1024, 0, stream>>>(cntI, offs);
    k_bin<<<NROWS / 256, 256, 0, stream>>>(outIdx, offs, cursor, perm);
    k_dw_fused<<<KCODE, 256, 0, stream>>>(inputs, inv_in, perm, offs, cntI, emaw, csfin,
                                          outW, outE);
}

// Round 4
// 672.075 us; speedup vs baseline: 6.8663x; 1.5913x over previous
//
#include <hip/hip_runtime.h>
#include <math.h>

#define NROWS 32768
#define DIM   512
#define KCODE 8192
#define DECAYF 0.99f
#define OMDF   0.01f
#define EPSF   1e-5f
#define COMMITF 0.25f
#define MARGIN 8e-4f

typedef _Float16 half8 __attribute__((ext_vector_type(8)));
typedef _Float16 half4v __attribute__((ext_vector_type(4)));
typedef _Float16 half2v __attribute__((ext_vector_type(2)));
typedef float floatx16 __attribute__((ext_vector_type(16)));

// ws layout: see round-3 comment (unchanged).

__device__ __forceinline__ float block_sum_256(float v) {
    __shared__ float sm[4];
    int lane = threadIdx.x & 63, wave = threadIdx.x >> 6;
    #pragma unroll
    for (int off = 32; off; off >>= 1) v += __shfl_down(v, off);
    if (lane == 0) sm[wave] = v;
    __syncthreads();
    if (threadIdx.x == 0) v = sm[0] + sm[1] + sm[2] + sm[3];
    return v; // valid on thread 0 only
}

__global__ void k_rownorm_inv(const float* __restrict__ x, float* __restrict__ inv) {
    int wave = threadIdx.x >> 6;
    int lane = threadIdx.x & 63;
    int row = blockIdx.x * 4 + wave;
    const float* p = x + (size_t)row * DIM;
    float4 f1 = *(const float4*)&p[lane * 4];
    float4 f2 = *(const float4*)&p[256 + lane * 4];
    float s = f1.x*f1.x + f1.y*f1.y + f1.z*f1.z + f1.w*f1.w
            + f2.x*f2.x + f2.y*f2.y + f2.z*f2.z + f2.w*f2.w;
    #pragma unroll
    for (int off = 32; off; off >>= 1) s += __shfl_down(s, off);
    if (lane == 0) inv[row] = 1.0f / fmaxf(sqrtf(s), 1e-12f);
}

__global__ void k_split(const float* __restrict__ src, const float* __restrict__ inv,
                        _Float16* __restrict__ hi, _Float16* __restrict__ lo) {
    const int i4 = (blockIdx.x * 256 + threadIdx.x) * 4;
    const float iv = inv[i4 >> 9];
    const float4 v = *(const float4*)&src[i4];
    float n0 = v.x * iv, n1 = v.y * iv, n2 = v.z * iv, n3 = v.w * iv;
    _Float16 h0 = (_Float16)n0, h1 = (_Float16)n1, h2 = (_Float16)n2, h3 = (_Float16)n3;
    half4v hv = {h0, h1, h2, h3};
    *(half4v*)&hi[i4] = hv;
    half4v lv = {(_Float16)((n0 - (float)h0) * 4096.f),
                 (_Float16)((n1 - (float)h1) * 4096.f),
                 (_Float16)((n2 - (float)h2) * 4096.f),
                 (_Float16)((n3 - (float)h3) * 4096.f)};
    *(half4v*)&lo[i4] = lv;
}

__device__ __forceinline__ void gld16(const _Float16* g, _Float16* l) {
    __builtin_amdgcn_global_load_lds(
        (const __attribute__((address_space(1))) void*)g,
        (__attribute__((address_space(3))) void*)l, 16, 0, 0);
}

__device__ __forceinline__ void top2_upd(float v, int i, float& v1, int& i1, float& v2) {
    if (v > v1) { v2 = v1; v1 = v; i1 = i; }
    else        { v2 = fmaxf(v2, v); }
}

// hi-only f16 screening pass. Block: 256 codes x 128 rows, wave tile 128x64
// (m=4,n=2). grid (256 row-tiles, 2 code-splits). LDS ~49KB -> 2 blocks/CU.
__launch_bounds__(256, 2)
__global__ void k_hi(const _Float16* __restrict__ Xh, const _Float16* __restrict__ Eh,
                     float* __restrict__ sV1, float* __restrict__ sV2,
                     unsigned short* __restrict__ sI1) {
    __shared__ __align__(16) _Float16 lds[24576];   // E [256][64] @0, X [128][64] @16384
    __shared__ float mV[128][2], mV2[128][2];
    __shared__ int   mI[128][2];

    const int tid  = threadIdx.x;
    const int w    = tid >> 6;
    const int lane = tid & 63;
    const int wc = w & 1, wr = w >> 1;
    const int c = lane & 31, h = lane >> 5;
    const int rowBase = blockIdx.x * 128;
    const int split   = blockIdx.y;
    const int sr = lane >> 3;
    const int sg = (lane & 7) ^ (sr & 7);
    const int cx = c & 7;
    const int rowB = wr * 64 + c;

    float v1a = -1e30f, v2a = -1e30f, v1b = -1e30f, v2b = -1e30f;
    int i1a = 0, i1b = 0;

    for (int nt = 0; nt < 16; ++nt) {
        const int ntBase = split * 4096 + nt * 256;
        floatx16 acc[4][2];
        #pragma unroll
        for (int i = 0; i < 4; ++i)
            #pragma unroll
            for (int j = 0; j < 2; ++j)
                #pragma unroll
                for (int r = 0; r < 16; ++r) acc[i][j][r] = 0.f;

        for (int chunk = 0; chunk < 8; ++chunk) {
            const int kt = chunk * 64;
            #pragma unroll
            for (int j = 0; j < 12; ++j) {
                const int u0 = w * 96 + j * 8;          // wave-uniform group base
                const int u  = u0 + sr;
                if (u0 < 256) {   // E rows
                    gld16(Eh + (size_t)(ntBase + u) * DIM + kt + sg * 8, &lds[u0 * 64]);
                } else {          // X rows
                    gld16(Xh + (size_t)(rowBase + u - 256) * DIM + kt + sg * 8,
                          &lds[16384 + (u0 - 256) * 64]);
                }
            }
            __syncthreads();
            #pragma unroll
            for (int ks = 0; ks < 4; ++ks) {
                const int so = ((ks * 2 + h) ^ cx) * 8;
                half8 a0 = *(const half8*)&lds[(wc * 128 + 0  + c) * 64 + so];
                half8 a1 = *(const half8*)&lds[(wc * 128 + 32 + c) * 64 + so];
                half8 a2 = *(const half8*)&lds[(wc * 128 + 64 + c) * 64 + so];
                half8 a3 = *(const half8*)&lds[(wc * 128 + 96 + c) * 64 + so];
                half8 b0 = *(const half8*)&lds[16384 + (rowB) * 64 + so];
                half8 b1 = *(const half8*)&lds[16384 + (rowB + 32) * 64 + so];
                acc[0][0] = __builtin_amdgcn_mfma_f32_32x32x16_f16(a0, b0, acc[0][0], 0, 0, 0);
                acc[1][0] = __builtin_amdgcn_mfma_f32_32x32x16_f16(a1, b0, acc[1][0], 0, 0, 0);
                acc[2][0] = __builtin_amdgcn_mfma_f32_32x32x16_f16(a2, b0, acc[2][0], 0, 0, 0);
                acc[3][0] = __builtin_amdgcn_mfma_f32_32x32x16_f16(a3, b0, acc[3][0], 0, 0, 0);
                acc[0][1] = __builtin_amdgcn_mfma_f32_32x32x16_f16(a0, b1, acc[0][1], 0, 0, 0);
                acc[1][1] = __builtin_amdgcn_mfma_f32_32x32x16_f16(a1, b1, acc[1][1], 0, 0, 0);
                acc[2][1] = __builtin_amdgcn_mfma_f32_32x32x16_f16(a2, b1, acc[2][1], 0, 0, 0);
                acc[3][1] = __builtin_amdgcn_mfma_f32_32x32x16_f16(a3, b1, acc[3][1], 0, 0, 0);
            }
            __syncthreads();
        }
        #pragma unroll
        for (int r = 0; r < 16; ++r) {
            const int codeSub = (r & 3) + ((r >> 2) << 3) + (h << 2);
            #pragma unroll
            for (int i = 0; i < 4; ++i) {
                const int code = ntBase + wc * 128 + i * 32 + codeSub;
                top2_upd(acc[i][0][r], code, v1a, i1a, v2a);
                top2_upd(acc[i][1][r], code, v1b, i1b, v2b);
            }
        }
    }

    // merge h-halves (disjoint code sets, same row)
    {
        float ov1 = __shfl_xor(v1a, 32); int oi1 = __shfl_xor(i1a, 32); float ov2 = __shfl_xor(v2a, 32);
        if (ov1 > v1a) { v2a = fmaxf(v1a, ov2); v1a = ov1; i1a = oi1; }
        else if (ov1 == v1a) { v2a = v1a; if (oi1 < i1a) i1a = oi1; }
        else { v2a = fmaxf(v2a, ov1); }
        ov1 = __shfl_xor(v1b, 32); oi1 = __shfl_xor(i1b, 32); ov2 = __shfl_xor(v2b, 32);
        if (ov1 > v1b) { v2b = fmaxf(v1b, ov2); v1b = ov1; i1b = oi1; }
        else if (ov1 == v1b) { v2b = v1b; if (oi1 < i1b) i1b = oi1; }
        else { v2b = fmaxf(v2b, ov1); }
    }
    if (h == 0) {
        mV[rowB][wc] = v1a; mV2[rowB][wc] = v2a; mI[rowB][wc] = i1a;
        mV[rowB + 32][wc] = v1b; mV2[rowB + 32][wc] = v2b; mI[rowB + 32][wc] = i1b;
    }
    __syncthreads();
    if (tid < 128) {
        float v1 = mV[tid][0], v2 = mV2[tid][0]; int i1 = mI[tid][0];
        float ov1 = mV[tid][1], ov2 = mV2[tid][1]; int oi1 = mI[tid][1];
        if (ov1 > v1) { v2 = fmaxf(v1, ov2); v1 = ov1; i1 = oi1; }
        else if (ov1 == v1) { v2 = v1; if (oi1 < i1) i1 = oi1; }
        else { v2 = fmaxf(v2, ov1); }
        const int n = rowBase + tid;
        sV1[split * NROWS + n] = v1;
        sV2[split * NROWS + n] = v2;
        sI1[split * NROWS + n] = (unsigned short)i1;
    }
}

__global__ void k_top2_merge(const float* __restrict__ sV1, const float* __restrict__ sV2,
                             const unsigned short* __restrict__ sI1,
                             float* __restrict__ outIdx, int* __restrict__ list,
                             int* __restrict__ flagCnt) {
    const int n = blockIdx.x * 256 + threadIdx.x;
    float a1 = sV1[n], a2 = sV2[n]; int ai = sI1[n];
    float b1 = sV1[NROWS + n], b2 = sV2[NROWS + n]; int bi = sI1[NROWS + n];
    float best, run; int bidx;
    if (b1 > a1) { best = b1; bidx = bi; run = fmaxf(a1, b2); }
    else         { best = a1; bidx = ai; run = fmaxf(a2, b1); }
    outIdx[n] = (float)bidx;
    if (best - run < MARGIN) {
        int p = atomicAdd(flagCnt, 1);
        list[p] = n;
    }
}

__device__ __forceinline__ unsigned long long encodeKey(float v, int idx) {
    unsigned u = __float_as_uint(v);
    u = (u & 0x80000000u) ? ~u : (u | 0x80000000u);
    return ((unsigned long long)u << 32) | (unsigned)(0xFFFFFFFFu - (unsigned)idx);
}

// dual-precision rescore of flagged rows (r2-identical numerics).
__launch_bounds__(256, 2)
__global__ void k_rescore(const _Float16* __restrict__ Xh, const _Float16* __restrict__ Xl,
                          const _Float16* __restrict__ Eh, const _Float16* __restrict__ El,
                          const int* __restrict__ list, const int* __restrict__ flagCnt,
                          unsigned long long* __restrict__ rkey) {
    const int cnt = *flagCnt;
    const int t = blockIdx.x & 255;
    const int s = blockIdx.x >> 8;
    if (t * 128 >= cnt) return;

    __shared__ __align__(16) _Float16 lds[32768];  // Eh|El|Xh|Xl, 8192 halves each
    __shared__ float mV[128][2];
    __shared__ int   mI[128][2];

    const int tid  = threadIdx.x;
    const int w    = tid >> 6;
    const int lane = tid & 63;
    const int wc = w & 1, wr = w >> 1;
    const int c = lane & 31, h = lane >> 5;
    const int sr = lane >> 3;
    const int sg = (lane & 7) ^ (sr & 7);
    const int rowA = wc * 64 + c;
    const int rowB = wr * 64 + c;
    const int cx = c & 7;

    int rows_j[4];
    #pragma unroll
    for (int j = 0; j < 4; ++j) {
        const int slot = t * 128 + w * 32 + j * 8 + sr;
        rows_j[j] = (slot < cnt) ? list[slot] : 0;
    }

    float best0 = -1e30f, best1 = -1e30f;
    int bi0 = 0, bi1 = 0;
    const float SC = 1.0f / 4096.0f;

    for (int nt = 0; nt < 4; ++nt) {
        const int ntBase = s * 512 + nt * 128;

        floatx16 accH00, accH01, accH10, accH11, accC00, accC01, accC10, accC11;
        #pragma unroll
        for (int r = 0; r < 16; ++r) {
            accH00[r] = 0.f; accH01[r] = 0.f; accH10[r] = 0.f; accH11[r] = 0.f;
            accC00[r] = 0.f; accC01[r] = 0.f; accC10[r] = 0.f; accC11[r] = 0.f;
        }

        for (int chunk = 0; chunk < 8; ++chunk) {
            const int kt = chunk * 64;
            #pragma unroll
            for (int j = 0; j < 4; ++j) {
                const int rl = w * 32 + j * 8 + sr;
                const size_t gE = (size_t)(ntBase + rl) * DIM + kt + sg * 8;
                const size_t gX = (size_t)rows_j[j] * DIM + kt + sg * 8;
                _Float16* dBase = &lds[(w * 32 + j * 8) * 64];
                gld16(Eh + gE, dBase);
                gld16(El + gE, dBase + 8192);
                gld16(Xh + gX, dBase + 16384);
                gld16(Xl + gX, dBase + 24576);
            }
            __syncthreads();
            #pragma unroll
            for (int ks = 0; ks < 4; ++ks) {
                const int so = ((ks * 2 + h) ^ cx) * 8;
                const half8 ah0 = *(const half8*)&lds[rowA * 64 + so];
                const half8 ah1 = *(const half8*)&lds[(rowA + 32) * 64 + so];
                const half8 al0 = *(const half8*)&lds[8192 + rowA * 64 + so];
                const half8 al1 = *(const half8*)&lds[8192 + (rowA + 32) * 64 + so];
                const half8 bh0 = *(const half8*)&lds[16384 + rowB * 64 + so];
                const half8 bh1 = *(const half8*)&lds[16384 + (rowB + 32) * 64 + so];
                const half8 bl0 = *(const half8*)&lds[24576 + rowB * 64 + so];
                const half8 bl1 = *(const half8*)&lds[24576 + (rowB + 32) * 64 + so];

                accH00 = __builtin_amdgcn_mfma_f32_32x32x16_f16(ah0, bh0, accH00, 0, 0, 0);
                accC00 = __builtin_amdgcn_mfma_f32_32x32x16_f16(ah0, bl0, accC00, 0, 0, 0);
                accC00 = __builtin_amdgcn_mfma_f32_32x32x16_f16(al0, bh0, accC00, 0, 0, 0);

                accH01 = __builtin_amdgcn_mfma_f32_32x32x16_f16(ah0, bh1, accH01, 0, 0, 0);
                accC01 = __builtin_amdgcn_mfma_f32_32x32x16_f16(ah0, bl1, accC01, 0, 0, 0);
                accC01 = __builtin_amdgcn_mfma_f32_32x32x16_f16(al0, bh1, accC01, 0, 0, 0);

                accH10 = __builtin_amdgcn_mfma_f32_32x32x16_f16(ah1, bh0, accH10, 0, 0, 0);
                accC10 = __builtin_amdgcn_mfma_f32_32x32x16_f16(ah1, bl0, accC10, 0, 0, 0);
                accC10 = __builtin_amdgcn_mfma_f32_32x32x16_f16(al1, bh0, accC10, 0, 0, 0);

                accH11 = __builtin_amdgcn_mfma_f32_32x32x16_f16(ah1, bh1, accH11, 0, 0, 0);
                accC11 = __builtin_amdgcn_mfma_f32_32x32x16_f16(ah1, bl1, accC11, 0, 0, 0);
                accC11 = __builtin_amdgcn_mfma_f32_32x32x16_f16(al1, bh1, accC11, 0, 0, 0);
            }
            __syncthreads();
        }

        #pragma unroll
        for (int r = 0; r < 16; ++r) {
            const int codeSub = (r & 3) + ((r >> 2) << 3) + (h << 2);
            const int code0 = ntBase + wc * 64 + codeSub;
            const int code1 = code0 + 32;
            float v;
            v = fmaf(accC00[r], SC, accH00[r]);
            if (v > best0 || (v == best0 && code0 < bi0)) { best0 = v; bi0 = code0; }
            v = fmaf(accC10[r], SC, accH10[r]);
            if (v > best0 || (v == best0 && code1 < bi0)) { best0 = v; bi0 = code1; }
            v = fmaf(accC01[r], SC, accH01[r]);
            if (v > best1 || (v == best1 && code0 < bi1)) { best1 = v; bi1 = code0; }
            v = fmaf(accC11[r], SC, accH11[r]);
            if (v > best1 || (v == best1 && code1 < bi1)) { best1 = v; bi1 = code1; }
        }
    }

    {
        float ov = __shfl_xor(best0, 32); int oi = __shfl_xor(bi0, 32);
        if (ov > best0 || (ov == best0 && oi < bi0)) { best0 = ov; bi0 = oi; }
        ov = __shfl_xor(best1, 32); oi = __shfl_xor(bi1, 32);
        if (ov > best1 || (ov == best1 && oi < bi1)) { best1 = ov; bi1 = oi; }
    }
    if (h == 0) {
        mV[rowB][wc] = best0;      mI[rowB][wc] = bi0;
        mV[rowB + 32][wc] = best1; mI[rowB + 32][wc] = bi1;
    }
    __syncthreads();
    if (tid < 128) {
        const int slot = t * 128 + tid;
        if (slot < cnt) {
            float v0 = mV[tid][0]; int i0 = mI[tid][0];
            float v1 = mV[tid][1]; int i1 = mI[tid][1];
            float bv; int bidx;
            if (v1 > v0 || (v1 == v0 && i1 < i0)) { bv = v1; bidx = i1; }
            else                                  { bv = v0; bidx = i0; }
            atomicMax(&rkey[list[slot]], encodeKey(bv, bidx));
        }
    }
}

__global__ void k_rescore_merge(const unsigned long long* __restrict__ rkey,
                                const int* __restrict__ list, const int* __restrict__ flagCnt,
                                float* __restrict__ outIdx) {
    const int slot = blockIdx.x * 256 + threadIdx.x;
    if (slot < *flagCnt) {
        const int row = list[slot];
        const unsigned long long key = rkey[row];
        const int code = (int)(0xFFFFFFFFu - (unsigned)(key & 0xFFFFFFFFull));
        outIdx[row] = (float)code;
    }
}

__global__ void k_hist(const float* __restrict__ outIdx, int* __restrict__ cntI) {
    const int n = blockIdx.x * 256 + threadIdx.x;
    atomicAdd(&cntI[(int)outIdx[n]], 1);
}

// grid-strided gather + loss: 2048 blocks x 256 threads, 8 float4-groups/thread.
// Coalesced 16B/lane stream of X/qst; Eh/El gathers hit LLC (16 MB resident).
// One atomic per block (2048 total, was 32768).
__global__ void k_gather_loss(const float* __restrict__ X, const _Float16* __restrict__ Eh,
                              const _Float16* __restrict__ El, const float* __restrict__ outIdx,
                              float* __restrict__ qst, float* __restrict__ lossAcc) {
    const float SC = 1.0f / 4096.0f;
    float acc = 0.f;
    #pragma unroll
    for (int it = 0; it < 8; ++it) {
        const int e = (it * 2048 + blockIdx.x) * 256 + threadIdx.x;   // float4 index
        const int row = e >> 7;                                       // 128 float4 per row
        const int col = (e & 127) * 4;
        const int k = (int)outIdx[row];
        const float4 x = ((const float4*)X)[e];
        const half4v eh = *(const half4v*)&Eh[(size_t)k * DIM + col];
        const half4v el = *(const half4v*)&El[(size_t)k * DIM + col];
        const float q0 = (float)eh.x + (float)el.x * SC;
        const float q1 = (float)eh.y + (float)el.y * SC;
        const float q2 = (float)eh.z + (float)el.z * SC;
        const float q3 = (float)eh.w + (float)el.w * SC;
        const float d0 = q0 - x.x, d1 = q1 - x.y, d2 = q2 - x.z, d3 = q3 - x.w;
        float4 o; o.x = x.x + d0; o.y = x.y + d1; o.z = x.z + d2; o.w = x.w + d3;
        ((float4*)qst)[e] = o;
        acc += d0 * d0 + d1 * d1 + d2 * d2 + d3 * d3;
    }
    const float ls = block_sum_256(acc);
    if (threadIdx.x == 0) atomicAdd(lossAcc, ls);
}

__global__ void k_cs_pre(const float* __restrict__ emacs, const int* __restrict__ cntI,
                         float* __restrict__ pre, float* __restrict__ nsum) {
    const int k = blockIdx.x * 256 + threadIdx.x;
    float p = emacs[k] * DECAYF + OMDF * (float)cntI[k];
    pre[k] = p;
    float s = block_sum_256(p);
    if (threadIdx.x == 0) atomicAdd(nsum, s);
}

__global__ void k_cs_final(const float* __restrict__ pre, const float* __restrict__ nsum,
                           float* __restrict__ outCS, float* __restrict__ csfin,
                           const float* __restrict__ lossAcc, float* __restrict__ outLoss) {
    const int k = blockIdx.x * 256 + threadIdx.x;
    float n = *nsum;
    float c = (pre[k] + EPSF) / (n + (float)KCODE * EPSF) * n;
    outCS[k] = c;
    csfin[k] = c;
    if (k == 0) *outLoss = COMMITF * (*lossAcc) / (float)(NROWS * DIM);
}

__global__ void k_scan(const int* __restrict__ cntI, int* __restrict__ offs) {
    __shared__ int ps[1024];
    const int t = threadIdx.x;
    int loc[8], pref[8], s = 0;
    #pragma unroll
    for (int j = 0; j < 8; ++j) { loc[j] = cntI[t * 8 + j]; pref[j] = s; s += loc[j]; }
    ps[t] = s;
    __syncthreads();
    for (int d = 1; d < 1024; d <<= 1) {
        int x = (t >= d) ? ps[t - d] : 0;
        __syncthreads();
        ps[t] += x;
        __syncthreads();
    }
    const int base = ps[t] - s;
    #pragma unroll
    for (int j = 0; j < 8; ++j) offs[t * 8 + j] = base + pref[j];
}

__global__ void k_bin(const float* __restrict__ outIdx, const int* __restrict__ offs,
                      int* __restrict__ cursor, int* __restrict__ perm) {
    const int n = blockIdx.x * 256 + threadIdx.x;
    const int k = (int)outIdx[n];
    const int pos = offs[k] + atomicAdd(&cursor[k], 1);
    perm[pos] = n;
}

// one block per code: dw accumulation + EMA weight + embedding, fused.
__global__ void k_dw_fused(const float* __restrict__ X, const float* __restrict__ inv_in,
                           const int* __restrict__ perm, const int* __restrict__ offs,
                           const int* __restrict__ cntI, const float* __restrict__ emaw,
                           const float* __restrict__ csfin,
                           float* __restrict__ outW, float* __restrict__ outE) {
    const int k = blockIdx.x;
    const int t = threadIdx.x;
    const int c = cntI[k];
    const int base = offs[k];
    float a0 = 0.f, a1 = 0.f;
    for (int i = 0; i < c; ++i) {
        const int row = perm[base + i];
        const float iv = inv_in[row];
        const float2 x = *(const float2*)&X[(size_t)row * DIM + t * 2];
        a0 = fmaf(x.x, iv, a0);
        a1 = fmaf(x.y, iv, a1);
    }
    const float2 w2 = *(const float2*)&emaw[(size_t)k * DIM + t * 2];
    const float w0 = w2.x * DECAYF + OMDF * a0;
    const float w1 = w2.y * DECAYF + OMDF * a1;
    float2 ow; ow.x = w0; ow.y = w1;
    *(float2*)&outW[(size_t)k * DIM + t * 2] = ow;
    const float cs = fmaxf(csfin[k], EPSF);
    float2 oe; oe.x = w0 / cs; oe.y = w1 / cs;
    *(float2*)&outE[(size_t)k * DIM + t * 2] = oe;
}

extern "C" void kernel_launch(void* const* d_in, const int* in_sizes, int n_in,
                              void* d_out, int out_size, void* d_ws, size_t ws_size,
                              hipStream_t stream) {
    const float* inputs    = (const float*)d_in[0];
    const float* embedding = (const float*)d_in[1];
    const float* emacs     = (const float*)d_in[2];
    const float* emaw      = (const float*)d_in[3];
    float* out = (float*)d_out;
    float* ws  = (float*)d_ws;

    float* inv_in  = ws;
    float* sV1     = ws + 32768;
    float* sV2     = ws + 98304;
    unsigned short* sI1 = (unsigned short*)(ws + 163840);
    int*   list    = (int*)(ws + 196608);
    int*   flagCnt = (int*)(ws + 229376);
    float* inv_emb = ws + 229440;            // overlays Xh head, dead before split_X
    _Float16* Xh   = (_Float16*)(ws + 229440);
    _Float16* Xl   = (_Float16*)(ws + 8618048);
    _Float16* Eh   = (_Float16*)(ws + 17006656);
    _Float16* El   = (_Float16*)(ws + 19103808);
    // overlays valid after k_top2_merge:
    unsigned long long* rkey = (unsigned long long*)(ws + 32768);
    int*   cntI    = (int*)(ws + 98304);
    int*   cursor  = (int*)(ws + 106496);
    float* lossAcc = ws + 114688;
    float* nsum    = ws + 114689;
    float* pre     = ws + 114692;
    float* csfin   = ws + 122884;
    int*   offs    = (int*)(ws + 131076);
    int*   perm    = (int*)(ws + 139268);

    float* outQst  = out;
    float* outLoss = out + 16777216;
    float* outIdx  = out + 16777217;
    float* outCS   = out + 16809985;
    float* outW    = out + 16818177;
    float* outE    = out + 21012481;

    hipMemsetAsync(flagCnt, 0, sizeof(int), stream);
    k_rownorm_inv<<<NROWS / 4, 256, 0, stream>>>(inputs, inv_in);
    k_rownorm_inv<<<KCODE / 4, 256, 0, stream>>>(embedding, inv_emb);
    k_split<<<KCODE * DIM / 1024, 256, 0, stream>>>(embedding, inv_emb, Eh, El);
    k_split<<<NROWS * DIM / 1024, 256, 0, stream>>>(inputs, inv_in, Xh, Xl);
    k_hi<<<dim3(NROWS / 128, 2), 256, 0, stream>>>(Xh, Eh, sV1, sV2, sI1);
    k_top2_merge<<<NROWS / 256, 256, 0, stream>>>(sV1, sV2, sI1, outIdx, list, flagCnt);
    // zero overlays: rkey(65536) + cntI(8192) + cursor(8192) + lossAcc + nsum
    hipMemsetAsync(ws + 32768, 0, (size_t)81922 * sizeof(float), stream);
    k_rescore<<<4096, 256, 0, stream>>>(Xh, Xl, Eh, El, list, flagCnt, rkey);
    k_rescore_merge<<<NROWS / 256, 256, 0, stream>>>(rkey, list, flagCnt, outIdx);
    k_hist<<<NROWS / 256, 256, 0, stream>>>(outIdx, cntI);
    k_gather_loss<<<2048, 256, 0, stream>>>(inputs, Eh, El, outIdx, outQst, lossAcc);
    k_cs_pre<<<KCODE / 256, 256, 0, stream>>>(emacs, cntI, pre, nsum);
    k_cs_final<<<KCODE / 256, 256, 0, stream>>>(pre, nsum, outCS, csfin, lossAcc, outLoss);
    k_scan<<<1, 1024, 0, stream>>>(cntI, offs);
    k_bin<<<NROWS / 256, 256, 0, stream>>>(outIdx, offs, cursor, perm);
    k_dw_fused<<<KCODE, 256, 0, stream>>>(inputs, inv_in, perm, offs, cntI, emaw, csfin,
                                          outW, outE);
}